// Round 18
// baseline (282.116 us; speedup 1.0000x reference)
//
#include <hip/hip_runtime.h>

#define TB 8
#define TC 64
#define TT 300
#define TDD 161
#define TH 128
#define TO 64
#define TN (TB * TDD)          // 1288 sequences
#define TWOH 256
#define TILE 16
#define NBLK 81                // ceil(1288/16)
#define NKS 6                  // (C+H)/32
#define ODCH (TO * TDD)        // 10304 channels
#define TOTAL (TB * TO * TT * TDD)      // 24729600
#define AFRAG (NKS * 4 * 16 * 8)        // 3072 ushorts per ring slot
#define TTD (TT * TDD)
#define LOG2E 1.44269504088896f

typedef __attribute__((ext_vector_type(8))) short bf16x8;
typedef __attribute__((ext_vector_type(4))) float f32x4;

#define MFMA __builtin_amdgcn_mfma_f32_16x16x32_bf16
#define EXP2R __builtin_amdgcn_exp2f   // raw v_exp_f32 (HW exp2), no libm wrapper

__device__ __forceinline__ ushort f2bf(float f) {
  union { float f; unsigned u; } v; v.f = f;
  return (ushort)((v.u + 0x7fffu + ((v.u >> 16) & 1u)) >> 16);  // RNE
}
__device__ __forceinline__ unsigned pk2bf(float lo, float hi) {
  unsigned r;
  asm("v_cvt_pk_bf16_f32 %0, %1, %2" : "=v"(r) : "v"(lo), "v"(hi));
  return r;
}

// k-mapping inside a 16x16x32 fragment; identical convention everywhere so any
// permutation error cancels in the contraction (verified R1-R17).
__device__ __forceinline__ int kmap(int e, int q) {
  return ((e < 4) ? 0 : 16) + q * 4 + (e & 3);
}

// 8-wave fused kernel (R15 structure: 4 gate-MFMA chains of depth 6).
// log2e folded into gate weights + RAW v_exp_f32 via __builtin_amdgcn_exp2f:
// sigmoid(a)=rcp(1+exp2(az)), tanh(b)=1-2*rcp(1+exp2(ac)).
// (R17's exp2f() was the libm call with edge-case code -> VALU regression.)
// Waves 0-3: recurrence only. Waves 4-7: y-consumers (4-step lag, 8-deep
// ring) + the entire x pipeline (register-renamed depth-4 rotation).
__global__ __launch_bounds__(512, 2) void gru_kernel(
    const float* __restrict__ x, const int* __restrict__ lengths,
    const float* __restrict__ Wx, const float* __restrict__ Wh,
    const float* __restrict__ bias, const float* __restrict__ Wo,
    const float* __restrict__ bo, float* __restrict__ out,
    float* __restrict__ wsStats)
{
  __shared__ __align__(16) ushort ring[8][AFRAG];   // [x_t | h_{t-1}] frags
  __shared__ float yts[4][16 * 17 + 4];             // per-y-wave transpose tile
  __shared__ int s_b[TILE], s_d[TILE], s_len[TILE], s_ok[TILE];

  const int tid = threadIdx.x;
  const int w = tid >> 6, l = tid & 63, q = l >> 4, r = l & 15;
  const int rxq = r ^ q;
  const int blk = blockIdx.x;

  if (tid < TILE) {
    int n = blk * TILE + tid;
    int ok = (n < TN) ? 1 : 0;
    int b = ok ? (n / TDD) : 0;
    int d = ok ? (n - b * TDD) : 0;
    s_b[tid] = b; s_d[tid] = d; s_ok[tid] = ok;
    s_len[tid] = ok ? lengths[b] : -1;
  }
  __syncthreads();
  // zero h-part of ring slot 0 (h_{-1} = 0), all threads
  for (int i = tid; i < AFRAG - 1024; i += 512) ring[0][1024 + i] = 0;

  // ---------------- role variables ----------------
  int xok = 0, xpos = 0;
  long xbase = 0;
  float xA[4], xB[4], xC[4], xD[4];
  bf16x8 wfz[2][NKS], wfc[2][NKS];
  float bz0 = 0, bz1 = 0, bc0 = 0, bc1 = 0;
  int llen[4], hwp[4];
  float hreg[2][4] = {{0, 0, 0, 0}, {0, 0, 0, 0}};
  bf16x8 wo4[4];
  float bo_v = 0;
  int nT = 0, dT = 0, lenT = -1, okT = 0;
  long ybaseT[4] = {0, 0, 0, 0};
  int ochT[4] = {0, 0, 0, 0};
  float ysumT[4] = {0, 0, 0, 0}, ysqT[4] = {0, 0, 0, 0};

#define XLD(T_, D_)                                                            \
  { int tt_ = (T_); tt_ = (tt_ < TT) ? tt_ : (TT - 1);                         \
    _Pragma("unroll")                                                          \
    for (int e = 0; e < 4; e++)                                                \
      D_[e] = xok ? x[xbase + (long)e * TTD + tt_ * TDD] : 0.0f; }

  if (w < 4) {
    // ---- recurrence wave setup: gate B-frags with log2e folded in.
    const int U = w * 32 + 2 * r;
    #pragma unroll
    for (int j = 0; j < 2; j++) {
      #pragma unroll
      for (int ks = 0; ks < NKS; ks++) {
        bf16x8 fz, fc;
        #pragma unroll
        for (int e = 0; e < 8; e++) {
          int kg = ks * 32 + kmap(e, q);
          const float* Wrow = (kg < TC) ? &Wx[kg * TWOH] : &Wh[(kg - TC) * TWOH];
          fz[e] = (short)f2bf(-LOG2E * Wrow[U + j]);
          fc[e] = (short)f2bf(2.0f * LOG2E * Wrow[TH + U + j]);
        }
        wfz[j][ks] = fz; wfc[j][ks] = fc;
      }
    }
    bz0 = -LOG2E * bias[U]; bz1 = -LOG2E * bias[U + 1];
    bc0 = 2.0f * LOG2E * bias[TH + U]; bc1 = 2.0f * LOG2E * bias[TH + U + 1];
    #pragma unroll
    for (int i = 0; i < 4; i++) llen[i] = s_len[q * 4 + i];
    const int hqq = (r >> 1) & 3, hhalf = r >> 3, hem0 = (2 * r) & 3;
    #pragma unroll
    for (int i = 0; i < 4; i++)
      hwp[i] = (((2 + w) * 4 + hqq) * 16 + ((q * 4 + i) ^ hqq)) * 8
               + hhalf * 4 + hem0;
  } else {
    // ---- y-wave setup: Wo frags + transposed-store info
    const int w4 = w - 4;
    #pragma unroll
    for (int ks = 0; ks < 4; ks++) {
      bf16x8 f;
      #pragma unroll
      for (int e = 0; e < 8; e++)
        f[e] = (short)f2bf(Wo[(ks * 32 + kmap(e, q)) * TO + w4 * 16 + r]);
      wo4[ks] = f;
    }
    bo_v = bo[w4 * 16 + r];
    nT = l & 15;
    dT = s_d[nT]; lenT = s_len[nT]; okT = s_ok[nT];
    #pragma unroll
    for (int j = 0; j < 4; j++) {
      int oj = w4 * 16 + (l >> 4) + 4 * j;
      ybaseT[j] = (long)(s_b[nT] * TO + oj) * TTD + dT;
      ochT[j] = oj * TDD + dT;
    }
    // ---- x pipeline (256 y-threads): slot nn = tid2&15, cq = tid2>>4
    const int tid2 = tid - 256;
    const int xnn = tid2 & 15, xcq = tid2 >> 4;
    xok = s_ok[xnn];
    xbase = (long)(s_b[xnn] * TC + xcq * 4) * TTD + s_d[xnn];
    xpos = (((xcq >> 3) * 4 + (xcq & 3)) * 16 + (xnn ^ (xcq & 3))) * 8
           + ((xcq >> 2) & 1) * 4;
    {  // stage x(0) into ring slot 0
      float cx[4]; XLD(0, cx)
      uint2 pv; pv.x = pk2bf(cx[0], cx[1]); pv.y = pk2bf(cx[2], cx[3]);
      *(uint2*)&ring[0][xpos] = pv;
    }
    XLD(1, xA) XLD(2, xB) XLD(3, xC) XLD(4, xD)
  }
  __syncthreads();

// ---- y-consumer body: y_{tm} from h_{tm} in ring slot (tm+1)&7
#define YB(TM_)                                                                \
  {                                                                            \
    const int tm_ = (TM_);                                                     \
    const ushort* Ah = ring[(tm_ + 1) & 7];                                    \
    bf16x8 ah0 = *(const bf16x8*)&Ah[((2 * 4 + q) * 16 + rxq) * 8];            \
    bf16x8 ah1 = *(const bf16x8*)&Ah[((3 * 4 + q) * 16 + rxq) * 8];            \
    bf16x8 ah2 = *(const bf16x8*)&Ah[((4 * 4 + q) * 16 + rxq) * 8];            \
    bf16x8 ah3 = *(const bf16x8*)&Ah[((5 * 4 + q) * 16 + rxq) * 8];            \
    f32x4 ya = {bo_v, bo_v, bo_v, bo_v};                                       \
    ya = MFMA(ah0, wo4[0], ya, 0, 0, 0);                                       \
    ya = MFMA(ah1, wo4[1], ya, 0, 0, 0);                                       \
    ya = MFMA(ah2, wo4[2], ya, 0, 0, 0);                                       \
    ya = MFMA(ah3, wo4[3], ya, 0, 0, 0);                                       \
    float* yt = yts[w - 4];                                                    \
    _Pragma("unroll")                                                          \
    for (int i = 0; i < 4; i++) yt[r * 17 + q * 4 + i] = ya[i];                \
    _Pragma("unroll")                                                          \
    for (int j = 0; j < 4; j++) {                                              \
      float v = yt[((l >> 4) + 4 * j) * 17 + nT];                              \
      if (okT) out[ybaseT[j] + (long)tm_ * TDD] = v;                           \
      bool val = (tm_ < lenT);                                                 \
      ysumT[j] += val ? v : 0.0f;                                              \
      ysqT[j]  += val ? v * v : 0.0f;                                          \
    }                                                                          \
  }

#define SUB(T_, XR)                                                            \
  {                                                                            \
    const int t_ = (T_);                                                       \
    if (w < 4) {                                                               \
      const ushort* Ab = ring[t_ & 7];                                         \
      bf16x8 af0 = *(const bf16x8*)&Ab[((0 * 4 + q) * 16 + rxq) * 8];          \
      bf16x8 af1 = *(const bf16x8*)&Ab[((1 * 4 + q) * 16 + rxq) * 8];          \
      bf16x8 af2 = *(const bf16x8*)&Ab[((2 * 4 + q) * 16 + rxq) * 8];          \
      bf16x8 af3 = *(const bf16x8*)&Ab[((3 * 4 + q) * 16 + rxq) * 8];          \
      bf16x8 af4 = *(const bf16x8*)&Ab[((4 * 4 + q) * 16 + rxq) * 8];          \
      bf16x8 af5 = *(const bf16x8*)&Ab[((5 * 4 + q) * 16 + rxq) * 8];          \
      f32x4 az0 = {bz0, bz0, bz0, bz0}, az1 = {bz1, bz1, bz1, bz1};            \
      f32x4 ac0 = {bc0, bc0, bc0, bc0}, ac1 = {bc1, bc1, bc1, bc1};            \
      __builtin_amdgcn_s_setprio(1);                                           \
      az0 = MFMA(af0, wfz[0][0], az0, 0, 0, 0);                                \
      az1 = MFMA(af0, wfz[1][0], az1, 0, 0, 0);                                \
      ac0 = MFMA(af0, wfc[0][0], ac0, 0, 0, 0);                                \
      ac1 = MFMA(af0, wfc[1][0], ac1, 0, 0, 0);                                \
      az0 = MFMA(af1, wfz[0][1], az0, 0, 0, 0);                                \
      az1 = MFMA(af1, wfz[1][1], az1, 0, 0, 0);                                \
      ac0 = MFMA(af1, wfc[0][1], ac0, 0, 0, 0);                                \
      ac1 = MFMA(af1, wfc[1][1], ac1, 0, 0, 0);                                \
      az0 = MFMA(af2, wfz[0][2], az0, 0, 0, 0);                                \
      az1 = MFMA(af2, wfz[1][2], az1, 0, 0, 0);                                \
      ac0 = MFMA(af2, wfc[0][2], ac0, 0, 0, 0);                                \
      ac1 = MFMA(af2, wfc[1][2], ac1, 0, 0, 0);                                \
      az0 = MFMA(af3, wfz[0][3], az0, 0, 0, 0);                                \
      az1 = MFMA(af3, wfz[1][3], az1, 0, 0, 0);                                \
      ac0 = MFMA(af3, wfc[0][3], ac0, 0, 0, 0);                                \
      ac1 = MFMA(af3, wfc[1][3], ac1, 0, 0, 0);                                \
      az0 = MFMA(af4, wfz[0][4], az0, 0, 0, 0);                                \
      az1 = MFMA(af4, wfz[1][4], az1, 0, 0, 0);                                \
      ac0 = MFMA(af4, wfc[0][4], ac0, 0, 0, 0);                                \
      ac1 = MFMA(af4, wfc[1][4], ac1, 0, 0, 0);                                \
      az0 = MFMA(af5, wfz[0][5], az0, 0, 0, 0);                                \
      az1 = MFMA(af5, wfz[1][5], az1, 0, 0, 0);                                \
      ac0 = MFMA(af5, wfc[0][5], ac0, 0, 0, 0);                                \
      ac1 = MFMA(af5, wfc[1][5], ac1, 0, 0, 0);                                \
      __builtin_amdgcn_s_setprio(0);                                           \
      _Pragma("unroll")                                                        \
      for (int i = 0; i < 4; i++) {                                            \
        float zv = __builtin_amdgcn_rcpf(1.0f + EXP2R(az0[i]));                \
        float hc = 1.0f - 2.0f * __builtin_amdgcn_rcpf(1.0f + EXP2R(ac0[i]));  \
        float h  = hc + zv * (hreg[0][i] - hc);                                \
        hreg[0][i] = (t_ < llen[i]) ? h : hreg[0][i];                          \
        zv = __builtin_amdgcn_rcpf(1.0f + EXP2R(az1[i]));                      \
        hc = 1.0f - 2.0f * __builtin_amdgcn_rcpf(1.0f + EXP2R(ac1[i]));        \
        h  = hc + zv * (hreg[1][i] - hc);                                      \
        hreg[1][i] = (t_ < llen[i]) ? h : hreg[1][i];                          \
      }                                                                        \
      ushort* Aw = ring[(t_ + 1) & 7];                                         \
      *(unsigned*)&Aw[hwp[0]] = pk2bf(hreg[0][0], hreg[1][0]);                 \
      *(unsigned*)&Aw[hwp[1]] = pk2bf(hreg[0][1], hreg[1][1]);                 \
      *(unsigned*)&Aw[hwp[2]] = pk2bf(hreg[0][2], hreg[1][2]);                 \
      *(unsigned*)&Aw[hwp[3]] = pk2bf(hreg[0][3], hreg[1][3]);                 \
    } else {                                                                   \
      {  /* stage x(t_+1) into ring[(t_+1)&7]; reissue XR for t_+5 */          \
        uint2 pv; pv.x = pk2bf(XR[0], XR[1]); pv.y = pk2bf(XR[2], XR[3]);      \
        *(uint2*)&ring[(t_ + 1) & 7][xpos] = pv;                               \
      }                                                                        \
      XLD(t_ + 5, XR)                                                          \
      if (t_ >= 4) { YB(t_ - 4) }                                              \
    }                                                                          \
    asm volatile("s_waitcnt lgkmcnt(0)" ::: "memory");                         \
    __builtin_amdgcn_s_barrier();                                              \
    __builtin_amdgcn_sched_barrier(0);                                         \
  }

  for (int t = 0; t < TT; t += 4) {   // TT = 300, multiple of 4
    SUB(t + 0, xA)
    SUB(t + 1, xB)
    SUB(t + 2, xC)
    SUB(t + 3, xD)
  }
#undef SUB
#undef XLD

  // epilogue: y_{TT-4..TT-1} (ring slots still live), then stats flush
  if (w >= 4) {
    YB(TT - 4) YB(TT - 3) YB(TT - 2) YB(TT - 1)
    #pragma unroll
    for (int j = 0; j < 4; j++) {
      if (okT) {
        atomicAdd(&wsStats[ochT[j]], ysumT[j]);
        atomicAdd(&wsStats[ODCH + ochT[j]], ysqT[j]);
      }
    }
  }
#undef YB
}

// ---------------- BN finalize: per-channel scale/shift ------------------
__global__ __launch_bounds__(256) void finalize_kernel(
    const int* __restrict__ lengths, const float* __restrict__ gamma,
    const float* __restrict__ beta, float* __restrict__ wsStats)
{
  int ch = blockIdx.x * 256 + threadIdx.x;
  if (ch >= ODCH) return;
  int c = 0;
  #pragma unroll
  for (int b = 0; b < TB; b++) c += lengths[b];
  float inv = 1.0f / (float)c;
  float mean = wsStats[ch] * inv;
  float var = wsStats[ODCH + ch] * inv - mean * mean;
  float sc = rsqrtf(var + 1e-5f) * gamma[ch];
  wsStats[2 * ODCH + ch] = sc;
  wsStats[3 * ODCH + ch] = beta[ch] - mean * sc;
}

// ---------------- normalize (float4, scale/shift table) ------------------
__global__ __launch_bounds__(256) void norm_kernel(
    const int* __restrict__ lengths, const float* __restrict__ ss,
    float* __restrict__ out)
{
  int i4 = blockIdx.x * 256 + threadIdx.x;   // TOTAL/4 exact
  int idx = i4 * 4;
  float vv[4];
  *(float4*)vv = ((const float4*)out)[i4];
  int dq = idx / TDD; int d = idx - dq * TDD;
  int tq = dq / TT;   int tt = dq - tq * TT;
  int o = tq & 63;    int b = tq >> 6;
  float res[4];
  #pragma unroll
  for (int k = 0; k < 4; k++) {
    int ch = o * TDD + d;
    float r_ = 0.0f;
    if (tt < lengths[b])
      r_ = vv[k] * ss[ch] + ss[ODCH + ch];
    res[k] = r_;
    d++;
    if (d == TDD) { d = 0; tt++; if (tt == TT) { tt = 0; o++; if (o == 64) { o = 0; b++; } } }
  }
  ((float4*)out)[i4] = *(float4*)res;
}

extern "C" void kernel_launch(void* const* d_in, const int* in_sizes, int n_in,
                              void* d_out, int out_size, void* d_ws, size_t ws_size,
                              hipStream_t stream)
{
  const float* x       = (const float*)d_in[0];
  const int*   lengths = (const int*)d_in[1];
  const float* Wx      = (const float*)d_in[2];
  const float* Wh      = (const float*)d_in[3];
  const float* bias    = (const float*)d_in[4];
  const float* Wo      = (const float*)d_in[5];
  const float* bo      = (const float*)d_in[6];
  const float* gamma   = (const float*)d_in[7];
  const float* beta    = (const float*)d_in[8];
  float* out = (float*)d_out;
  float* wsStats = (float*)d_ws;   // 4*ODCH floats

  hipMemsetAsync(wsStats, 0, 2 * ODCH * sizeof(float), stream);
  hipLaunchKernelGGL(gru_kernel, dim3(NBLK), dim3(512), 0, stream,
                     x, lengths, Wx, Wh, bias, Wo, bo, out, wsStats);
  hipLaunchKernelGGL(finalize_kernel, dim3((ODCH + 255) / 256), dim3(256), 0, stream,
                     lengths, gamma, beta, wsStats);
  hipLaunchKernelGGL(norm_kernel, dim3(TOTAL / 4 / 256), dim3(256), 0, stream,
                     lengths, wsStats + 2 * ODCH, out);
}

// Round 19
// 234.834 us; speedup vs baseline: 1.2013x; 1.2013x over previous
//
#include <hip/hip_runtime.h>

#define TB 8
#define TC 64
#define TT 300
#define TDD 161
#define TH 128
#define TO 64
#define TN (TB * TDD)          // 1288 sequences
#define TWOH 256
#define TILE 16
#define NBLK 81                // ceil(1288/16)
#define NKS 6                  // (C+H)/32
#define ODCH (TO * TDD)        // 10304 channels
#define TOTAL (TB * TO * TT * TDD)      // 24729600
#define AFRAG (NKS * 4 * 16 * 8)        // 3072 ushorts per ring slot
#define TTD (TT * TDD)

typedef __attribute__((ext_vector_type(8))) short bf16x8;
typedef __attribute__((ext_vector_type(4))) float f32x4;

#define MFMA __builtin_amdgcn_mfma_f32_16x16x32_bf16

__device__ __forceinline__ ushort f2bf(float f) {
  union { float f; unsigned u; } v; v.f = f;
  return (ushort)((v.u + 0x7fffu + ((v.u >> 16) & 1u)) >> 16);  // RNE
}
__device__ __forceinline__ unsigned pk2bf(float lo, float hi) {
  unsigned r;
  asm("v_cvt_pk_bf16_f32 %0, %1, %2" : "=v"(r) : "v"(lo), "v"(hi));
  return r;
}

// k-mapping inside a 16x16x32 fragment; identical convention everywhere so any
// permutation error cancels in the contraction (verified R1-R18).
__device__ __forceinline__ int kmap(int e, int q) {
  return ((e < 4) ? 0 : 16) + q * 4 + (e & 3);
}

// 8-wave fused kernel — K15, the best-measured variant (236 µs headline).
// Waves 0-3: recurrence only (4 gate-MFMA chains of depth 6, __expf gates,
// c-gate weights pre-scaled by 2). Waves 4-7: y-consumers (4-step lag via
// 8-deep LDS ring) + the entire x pipeline (register-renamed depth-4
// rotation, d-adjacent coalesced gather). lgkm-only barrier per step.
__global__ __launch_bounds__(512, 2) void gru_kernel(
    const float* __restrict__ x, const int* __restrict__ lengths,
    const float* __restrict__ Wx, const float* __restrict__ Wh,
    const float* __restrict__ bias, const float* __restrict__ Wo,
    const float* __restrict__ bo, float* __restrict__ out,
    float* __restrict__ wsStats)
{
  __shared__ __align__(16) ushort ring[8][AFRAG];   // [x_t | h_{t-1}] frags
  __shared__ float yts[4][16 * 17 + 4];             // per-y-wave transpose tile
  __shared__ int s_b[TILE], s_d[TILE], s_len[TILE], s_ok[TILE];

  const int tid = threadIdx.x;
  const int w = tid >> 6, l = tid & 63, q = l >> 4, r = l & 15;
  const int rxq = r ^ q;
  const int blk = blockIdx.x;

  if (tid < TILE) {
    int n = blk * TILE + tid;
    int ok = (n < TN) ? 1 : 0;
    int b = ok ? (n / TDD) : 0;
    int d = ok ? (n - b * TDD) : 0;
    s_b[tid] = b; s_d[tid] = d; s_ok[tid] = ok;
    s_len[tid] = ok ? lengths[b] : -1;
  }
  __syncthreads();
  // zero h-part of ring slot 0 (h_{-1} = 0), all threads
  for (int i = tid; i < AFRAG - 1024; i += 512) ring[0][1024 + i] = 0;

  // ---------------- role variables ----------------
  int xok = 0, xpos = 0;
  long xbase = 0;
  float xA[4], xB[4], xC[4], xD[4];
  bf16x8 wfz[2][NKS], wfc[2][NKS];
  float bz0 = 0, bz1 = 0, bc0 = 0, bc1 = 0;
  int llen[4], hwp[4];
  float hreg[2][4] = {{0, 0, 0, 0}, {0, 0, 0, 0}};
  bf16x8 wo4[4];
  float bo_v = 0;
  int nT = 0, dT = 0, lenT = -1, okT = 0;
  long ybaseT[4] = {0, 0, 0, 0};
  int ochT[4] = {0, 0, 0, 0};
  float ysumT[4] = {0, 0, 0, 0}, ysqT[4] = {0, 0, 0, 0};

#define XLD(T_, D_)                                                            \
  { int tt_ = (T_); tt_ = (tt_ < TT) ? tt_ : (TT - 1);                         \
    _Pragma("unroll")                                                          \
    for (int e = 0; e < 4; e++)                                                \
      D_[e] = xok ? x[xbase + (long)e * TTD + tt_ * TDD] : 0.0f; }

  if (w < 4) {
    // ---- recurrence wave setup: gate B-frags; c pre-scaled by 2 (exact)
    const int U = w * 32 + 2 * r;
    #pragma unroll
    for (int j = 0; j < 2; j++) {
      #pragma unroll
      for (int ks = 0; ks < NKS; ks++) {
        bf16x8 fz, fc;
        #pragma unroll
        for (int e = 0; e < 8; e++) {
          int kg = ks * 32 + kmap(e, q);
          const float* Wrow = (kg < TC) ? &Wx[kg * TWOH] : &Wh[(kg - TC) * TWOH];
          fz[e] = (short)f2bf(Wrow[U + j]);
          fc[e] = (short)f2bf(2.0f * Wrow[TH + U + j]);
        }
        wfz[j][ks] = fz; wfc[j][ks] = fc;
      }
    }
    bz0 = bias[U]; bz1 = bias[U + 1];
    bc0 = 2.0f * bias[TH + U]; bc1 = 2.0f * bias[TH + U + 1];
    #pragma unroll
    for (int i = 0; i < 4; i++) llen[i] = s_len[q * 4 + i];
    const int hqq = (r >> 1) & 3, hhalf = r >> 3, hem0 = (2 * r) & 3;
    #pragma unroll
    for (int i = 0; i < 4; i++)
      hwp[i] = (((2 + w) * 4 + hqq) * 16 + ((q * 4 + i) ^ hqq)) * 8
               + hhalf * 4 + hem0;
  } else {
    // ---- y-wave setup: Wo frags + transposed-store info
    const int w4 = w - 4;
    #pragma unroll
    for (int ks = 0; ks < 4; ks++) {
      bf16x8 f;
      #pragma unroll
      for (int e = 0; e < 8; e++)
        f[e] = (short)f2bf(Wo[(ks * 32 + kmap(e, q)) * TO + w4 * 16 + r]);
      wo4[ks] = f;
    }
    bo_v = bo[w4 * 16 + r];
    nT = l & 15;
    dT = s_d[nT]; lenT = s_len[nT]; okT = s_ok[nT];
    #pragma unroll
    for (int j = 0; j < 4; j++) {
      int oj = w4 * 16 + (l >> 4) + 4 * j;
      ybaseT[j] = (long)(s_b[nT] * TO + oj) * TTD + dT;
      ochT[j] = oj * TDD + dT;
    }
    // ---- x pipeline (256 y-threads): slot nn = tid2&15, cq = tid2>>4
    const int tid2 = tid - 256;
    const int xnn = tid2 & 15, xcq = tid2 >> 4;
    xok = s_ok[xnn];
    xbase = (long)(s_b[xnn] * TC + xcq * 4) * TTD + s_d[xnn];
    xpos = (((xcq >> 3) * 4 + (xcq & 3)) * 16 + (xnn ^ (xcq & 3))) * 8
           + ((xcq >> 2) & 1) * 4;
    {  // stage x(0) into ring slot 0
      float cx[4]; XLD(0, cx)
      uint2 pv; pv.x = pk2bf(cx[0], cx[1]); pv.y = pk2bf(cx[2], cx[3]);
      *(uint2*)&ring[0][xpos] = pv;
    }
    XLD(1, xA) XLD(2, xB) XLD(3, xC) XLD(4, xD)
  }
  __syncthreads();

// ---- y-consumer body: y_{tm} from h_{tm} in ring slot (tm+1)&7
#define YB(TM_)                                                                \
  {                                                                            \
    const int tm_ = (TM_);                                                     \
    const ushort* Ah = ring[(tm_ + 1) & 7];                                    \
    bf16x8 ah0 = *(const bf16x8*)&Ah[((2 * 4 + q) * 16 + rxq) * 8];            \
    bf16x8 ah1 = *(const bf16x8*)&Ah[((3 * 4 + q) * 16 + rxq) * 8];            \
    bf16x8 ah2 = *(const bf16x8*)&Ah[((4 * 4 + q) * 16 + rxq) * 8];            \
    bf16x8 ah3 = *(const bf16x8*)&Ah[((5 * 4 + q) * 16 + rxq) * 8];            \
    f32x4 ya = {bo_v, bo_v, bo_v, bo_v};                                       \
    ya = MFMA(ah0, wo4[0], ya, 0, 0, 0);                                       \
    ya = MFMA(ah1, wo4[1], ya, 0, 0, 0);                                       \
    ya = MFMA(ah2, wo4[2], ya, 0, 0, 0);                                       \
    ya = MFMA(ah3, wo4[3], ya, 0, 0, 0);                                       \
    float* yt = yts[w - 4];                                                    \
    _Pragma("unroll")                                                          \
    for (int i = 0; i < 4; i++) yt[r * 17 + q * 4 + i] = ya[i];                \
    _Pragma("unroll")                                                          \
    for (int j = 0; j < 4; j++) {                                              \
      float v = yt[((l >> 4) + 4 * j) * 17 + nT];                              \
      if (okT) out[ybaseT[j] + (long)tm_ * TDD] = v;                           \
      bool val = (tm_ < lenT);                                                 \
      ysumT[j] += val ? v : 0.0f;                                              \
      ysqT[j]  += val ? v * v : 0.0f;                                          \
    }                                                                          \
  }

#define SUB(T_, XR)                                                            \
  {                                                                            \
    const int t_ = (T_);                                                       \
    if (w < 4) {                                                               \
      const ushort* Ab = ring[t_ & 7];                                         \
      bf16x8 af0 = *(const bf16x8*)&Ab[((0 * 4 + q) * 16 + rxq) * 8];          \
      bf16x8 af1 = *(const bf16x8*)&Ab[((1 * 4 + q) * 16 + rxq) * 8];          \
      bf16x8 af2 = *(const bf16x8*)&Ab[((2 * 4 + q) * 16 + rxq) * 8];          \
      bf16x8 af3 = *(const bf16x8*)&Ab[((3 * 4 + q) * 16 + rxq) * 8];          \
      bf16x8 af4 = *(const bf16x8*)&Ab[((4 * 4 + q) * 16 + rxq) * 8];          \
      bf16x8 af5 = *(const bf16x8*)&Ab[((5 * 4 + q) * 16 + rxq) * 8];          \
      f32x4 az0 = {bz0, bz0, bz0, bz0}, az1 = {bz1, bz1, bz1, bz1};            \
      f32x4 ac0 = {bc0, bc0, bc0, bc0}, ac1 = {bc1, bc1, bc1, bc1};            \
      __builtin_amdgcn_s_setprio(1);                                           \
      az0 = MFMA(af0, wfz[0][0], az0, 0, 0, 0);                                \
      az1 = MFMA(af0, wfz[1][0], az1, 0, 0, 0);                                \
      ac0 = MFMA(af0, wfc[0][0], ac0, 0, 0, 0);                                \
      ac1 = MFMA(af0, wfc[1][0], ac1, 0, 0, 0);                                \
      az0 = MFMA(af1, wfz[0][1], az0, 0, 0, 0);                                \
      az1 = MFMA(af1, wfz[1][1], az1, 0, 0, 0);                                \
      ac0 = MFMA(af1, wfc[0][1], ac0, 0, 0, 0);                                \
      ac1 = MFMA(af1, wfc[1][1], ac1, 0, 0, 0);                                \
      az0 = MFMA(af2, wfz[0][2], az0, 0, 0, 0);                                \
      az1 = MFMA(af2, wfz[1][2], az1, 0, 0, 0);                                \
      ac0 = MFMA(af2, wfc[0][2], ac0, 0, 0, 0);                                \
      ac1 = MFMA(af2, wfc[1][2], ac1, 0, 0, 0);                                \
      az0 = MFMA(af3, wfz[0][3], az0, 0, 0, 0);                                \
      az1 = MFMA(af3, wfz[1][3], az1, 0, 0, 0);                                \
      ac0 = MFMA(af3, wfc[0][3], ac0, 0, 0, 0);                                \
      ac1 = MFMA(af3, wfc[1][3], ac1, 0, 0, 0);                                \
      az0 = MFMA(af4, wfz[0][4], az0, 0, 0, 0);                                \
      az1 = MFMA(af4, wfz[1][4], az1, 0, 0, 0);                                \
      ac0 = MFMA(af4, wfc[0][4], ac0, 0, 0, 0);                                \
      ac1 = MFMA(af4, wfc[1][4], ac1, 0, 0, 0);                                \
      az0 = MFMA(af5, wfz[0][5], az0, 0, 0, 0);                                \
      az1 = MFMA(af5, wfz[1][5], az1, 0, 0, 0);                                \
      ac0 = MFMA(af5, wfc[0][5], ac0, 0, 0, 0);                                \
      ac1 = MFMA(af5, wfc[1][5], ac1, 0, 0, 0);                                \
      __builtin_amdgcn_s_setprio(0);                                           \
      _Pragma("unroll")                                                        \
      for (int i = 0; i < 4; i++) {                                            \
        float zv = __builtin_amdgcn_rcpf(1.0f + __expf(-az0[i]));              \
        float hc = 1.0f - 2.0f * __builtin_amdgcn_rcpf(1.0f + __expf(ac0[i])); \
        float h  = hc + zv * (hreg[0][i] - hc);                                \
        hreg[0][i] = (t_ < llen[i]) ? h : hreg[0][i];                          \
        zv = __builtin_amdgcn_rcpf(1.0f + __expf(-az1[i]));                    \
        hc = 1.0f - 2.0f * __builtin_amdgcn_rcpf(1.0f + __expf(ac1[i]));       \
        h  = hc + zv * (hreg[1][i] - hc);                                      \
        hreg[1][i] = (t_ < llen[i]) ? h : hreg[1][i];                          \
      }                                                                        \
      ushort* Aw = ring[(t_ + 1) & 7];                                         \
      *(unsigned*)&Aw[hwp[0]] = pk2bf(hreg[0][0], hreg[1][0]);                 \
      *(unsigned*)&Aw[hwp[1]] = pk2bf(hreg[0][1], hreg[1][1]);                 \
      *(unsigned*)&Aw[hwp[2]] = pk2bf(hreg[0][2], hreg[1][2]);                 \
      *(unsigned*)&Aw[hwp[3]] = pk2bf(hreg[0][3], hreg[1][3]);                 \
    } else {                                                                   \
      {  /* stage x(t_+1) into ring[(t_+1)&7]; reissue XR for t_+5 */          \
        uint2 pv; pv.x = pk2bf(XR[0], XR[1]); pv.y = pk2bf(XR[2], XR[3]);      \
        *(uint2*)&ring[(t_ + 1) & 7][xpos] = pv;                               \
      }                                                                        \
      XLD(t_ + 5, XR)                                                          \
      if (t_ >= 4) { YB(t_ - 4) }                                              \
    }                                                                          \
    asm volatile("s_waitcnt lgkmcnt(0)" ::: "memory");                         \
    __builtin_amdgcn_s_barrier();                                              \
    __builtin_amdgcn_sched_barrier(0);                                         \
  }

  for (int t = 0; t < TT; t += 4) {   // TT = 300, multiple of 4
    SUB(t + 0, xA)
    SUB(t + 1, xB)
    SUB(t + 2, xC)
    SUB(t + 3, xD)
  }
#undef SUB
#undef XLD

  // epilogue: y_{TT-4..TT-1} (ring slots still live), then stats flush
  if (w >= 4) {
    YB(TT - 4) YB(TT - 3) YB(TT - 2) YB(TT - 1)
    #pragma unroll
    for (int j = 0; j < 4; j++) {
      if (okT) {
        atomicAdd(&wsStats[ochT[j]], ysumT[j]);
        atomicAdd(&wsStats[ODCH + ochT[j]], ysqT[j]);
      }
    }
  }
#undef YB
}

// ---------------- BN finalize: per-channel scale/shift ------------------
__global__ __launch_bounds__(256) void finalize_kernel(
    const int* __restrict__ lengths, const float* __restrict__ gamma,
    const float* __restrict__ beta, float* __restrict__ wsStats)
{
  int ch = blockIdx.x * 256 + threadIdx.x;
  if (ch >= ODCH) return;
  int c = 0;
  #pragma unroll
  for (int b = 0; b < TB; b++) c += lengths[b];
  float inv = 1.0f / (float)c;
  float mean = wsStats[ch] * inv;
  float var = wsStats[ODCH + ch] * inv - mean * mean;
  float sc = rsqrtf(var + 1e-5f) * gamma[ch];
  wsStats[2 * ODCH + ch] = sc;
  wsStats[3 * ODCH + ch] = beta[ch] - mean * sc;
}

// ---------------- normalize (float4, scale/shift table) ------------------
__global__ __launch_bounds__(256) void norm_kernel(
    const int* __restrict__ lengths, const float* __restrict__ ss,
    float* __restrict__ out)
{
  int i4 = blockIdx.x * 256 + threadIdx.x;   // TOTAL/4 exact
  int idx = i4 * 4;
  float vv[4];
  *(float4*)vv = ((const float4*)out)[i4];
  int dq = idx / TDD; int d = idx - dq * TDD;
  int tq = dq / TT;   int tt = dq - tq * TT;
  int o = tq & 63;    int b = tq >> 6;
  float res[4];
  #pragma unroll
  for (int k = 0; k < 4; k++) {
    int ch = o * TDD + d;
    float r_ = 0.0f;
    if (tt < lengths[b])
      r_ = vv[k] * ss[ch] + ss[ODCH + ch];
    res[k] = r_;
    d++;
    if (d == TDD) { d = 0; tt++; if (tt == TT) { tt = 0; o++; if (o == 64) { o = 0; b++; } } }
  }
  ((float4*)out)[i4] = *(float4*)res;
}

extern "C" void kernel_launch(void* const* d_in, const int* in_sizes, int n_in,
                              void* d_out, int out_size, void* d_ws, size_t ws_size,
                              hipStream_t stream)
{
  const float* x       = (const float*)d_in[0];
  const int*   lengths = (const int*)d_in[1];
  const float* Wx      = (const float*)d_in[2];
  const float* Wh      = (const float*)d_in[3];
  const float* bias    = (const float*)d_in[4];
  const float* Wo      = (const float*)d_in[5];
  const float* bo      = (const float*)d_in[6];
  const float* gamma   = (const float*)d_in[7];
  const float* beta    = (const float*)d_in[8];
  float* out = (float*)d_out;
  float* wsStats = (float*)d_ws;   // 4*ODCH floats

  hipMemsetAsync(wsStats, 0, 2 * ODCH * sizeof(float), stream);
  hipLaunchKernelGGL(gru_kernel, dim3(NBLK), dim3(512), 0, stream,
                     x, lengths, Wx, Wh, bias, Wo, bo, out, wsStats);
  hipLaunchKernelGGL(finalize_kernel, dim3((ODCH + 255) / 256), dim3(256), 0, stream,
                     lengths, gamma, beta, wsStats);
  hipLaunchKernelGGL(norm_kernel, dim3(TOTAL / 4 / 256), dim3(256), 0, stream,
                     lengths, wsStats + 2 * ODCH, out);
}